// Round 12
// baseline (47.260 us; speedup 1.0000x reference)
//
#include <hip/hip_runtime.h>
#include <hip/hip_bf16.h>

// LinearMinimumBit: y = x @ dequant3bit(W)^T + bias
// x:[64,8192] f32, weight_q3:[4194304,6] int32 (one byte value per int32),
// weight_norm:[4194304] f32, bias:[8192] f32 -> out:[64,8192] f32
//
// Round 12: round-8 TLP structure (BN=64, KS=16 -> 2048 blocks, 36.9 KB LDS,
// 4 blocks/CU) rebuilt on PROVEN primitives only. Round 8's failure is
// attributed to size=12 global_load_lds (dwordx3 lane-stride semantics
// unverified on gfx950). Packed weights now use 16B DMA + magic-div-96
// (the exact pattern that passed in rounds 6/7); norms use plain loads +
// LDS stores in the prologue.
//
// ws: [0,1MB) x as bf16; [1MB, 1MB+KS*2MB) partials [KS][64][8192] f32

#define BATCH   64
#define IN_F    8192
#define OUT_F   8192

#define PK_BYTES 6144    // packed weights/tile: 64 rows * 96 B (4 groups * 24 B)
#define PA_BYTES 8192    // A tile: 64 rows * 128 B (64 k * bf16), XOR-swizzled
#define BUF_BYTES (PK_BYTES + PA_BYTES)  // 14336

typedef __attribute__((ext_vector_type(8))) short bf16x8;
typedef __attribute__((ext_vector_type(4))) float f32x4;

__device__ __forceinline__ ushort f2bf(float f) {
  union { float f; unsigned u; } a; a.f = f;
  unsigned r = a.u + 0x7fffu + ((a.u >> 16) & 1u);
  return (ushort)(r >> 16);
}

__device__ __forceinline__ void gl_lds16(const void* g, void* l) {
  __builtin_amdgcn_global_load_lds((const __attribute__((address_space(1))) void*)g,
                                   (__attribute__((address_space(3))) void*)l, 16, 0, 0);
}

__global__ void __launch_bounds__(256) xcvt_kernel(const float* __restrict__ x,
                                                   ushort* __restrict__ xb) {
  int i = blockIdx.x * 256 + threadIdx.x;
  float4 v = ((const float4*)x)[i];
  ushort4 o;
  o.x = f2bf(v.x); o.y = f2bf(v.y); o.z = f2bf(v.z); o.w = f2bf(v.w);
  ((ushort4*)xb)[i] = o;
}

// 3 byte-values + norm -> 8 bf16 weights (w = v*(2n/7) - n), k-ascending
__device__ __forceinline__ bf16x8 dqfrag(int b0, int b1, int b2, float nrm) {
  float c1 = nrm * (2.0f / 7.0f);
  float c0 = nrm;
  int v0 = (b0 >> 5) & 7;
  int v1 = (b0 >> 2) & 7;
  int v2 = ((b0 & 3) << 1) | ((b1 >> 7) & 1);
  int v3 = (b1 >> 4) & 7;
  int v4 = (b1 >> 1) & 7;
  int v5 = ((b1 & 1) << 2) | ((b2 >> 6) & 3);
  int v6 = (b2 >> 3) & 7;
  int v7 = b2 & 7;
  union { __hip_bfloat162 h[4]; bf16x8 v; } r;
  r.h[0] = __float22bfloat162_rn(make_float2(fmaf((float)v0, c1, -c0), fmaf((float)v1, c1, -c0)));
  r.h[1] = __float22bfloat162_rn(make_float2(fmaf((float)v2, c1, -c0), fmaf((float)v3, c1, -c0)));
  r.h[2] = __float22bfloat162_rn(make_float2(fmaf((float)v4, c1, -c0), fmaf((float)v5, c1, -c0)));
  r.h[3] = __float22bfloat162_rn(make_float2(fmaf((float)v6, c1, -c0), fmaf((float)v7, c1, -c0)));
  return r.v;
}

template <int KS>
__global__ void __launch_bounds__(256) gemm3b_kernel(const ushort* __restrict__ xb,
                                                     const int* __restrict__ wq,
                                                     const float* __restrict__ wnorm,
                                                     float* __restrict__ partial) {
  constexpr int K_SLICE = IN_F / KS;      // 512 @KS=16
  constexpr int NTILE   = K_SLICE / 64;   // 8   @KS=16
  constexpr int NGROW   = K_SLICE / 16;   // norm groups per row per slice (32)

  __shared__ __align__(16) char  LDS[2][BUF_BYTES];
  __shared__ __align__(16) float NRM[64 * NGROW];   // 8 KB @KS=16

  const int tid  = threadIdx.x;
  const int lane = tid & 63;
  const int w    = tid >> 6;          // wave w owns cols [nb64 + w*16, +16)
  const int l15  = lane & 15;
  const int h    = lane >> 4;         // k-chunk within 32-k
  const int nb64 = blockIdx.x * 64;
  const int s    = blockIdx.y;
  const int kbase = s * K_SLICE;
  const int kg0   = kbase >> 4;

  const char*  wqp = (const char*)wq + (size_t)nb64 * 12288 + (size_t)kg0 * 24;
  const float* wnp = wnorm + (size_t)nb64 * 512 + kg0;
  const char*  xbp = (const char*)xb + (size_t)kbase * 2;

  f32x4 acc[4];
  #pragma unroll
  for (int m = 0; m < 4; ++m) acc[m] = (f32x4){0.f, 0.f, 0.f, 0.f};

  // --- prologue: stage all norms for this block's slice via PLAIN loads ---
  // NRM[row][NGROW] floats, linear. Visibility via the loop's first barrier.
  {
    constexpr int ROWB = NGROW * 4;             // bytes per norm row (128 @KS=16)
    constexpr int NDM  = (64 * ROWB) / 4096;    // float4 stores per thread (2 @KS=16)
    #pragma unroll
    for (int i = 0; i < NDM; ++i) {
      int t   = tid * 16 + i * 4096;
      int row = t / ROWB;                       // ROWB is pow2
      int off = t % ROWB;
      float4 v = *(const float4*)((const char*)wnp + (size_t)row * 2048 + off);
      *(float4*)((char*)NRM + t) = v;
    }
  }

  // pk chunk: 1024 B of the linear 6144-B tile image, 64 lanes x 16 B.
  // row = t/96 via magic mul (proven r6/r7); 16B loads never straddle a
  // 96-B row segment (16k mod 96 <= 80).
#define STAGE_PK_CHUNK(BUF, KT, C)                                            \
  do {                                                                        \
    int t   = (C) * 1024 + lane * 16;                                         \
    int row = (int)(((unsigned)t * 43691u) >> 22);                            \
    int off = t - row * 96;                                                   \
    gl_lds16(wqp + (size_t)row * 12288 + (KT) * 96 + off,                     \
             &LDS[BUF][(C) * 1024]);                                          \
  } while (0)

  // STAGE: pk 6144 B (6 wave-chunks) + A 8192 B (2 x 16B/thread), all 16B DMA
#define STAGE(BUF, KT)                                                        \
  do {                                                                        \
    STAGE_PK_CHUNK(BUF, KT, w);                                               \
    if (w < 2) STAGE_PK_CHUNK(BUF, KT, 4 + w);                                \
    _Pragma("unroll")                                                         \
    for (int i = 0; i < 2; ++i) {                                             \
      int row = (tid >> 3) + i * 32;                                          \
      int c   = tid & 7;                                                      \
      int cs  = c ^ (row & 7);                                                \
      gl_lds16(xbp + (size_t)row * (IN_F * 2) + (KT) * 128 + cs * 16,         \
               &LDS[BUF][PK_BYTES + i * 4096 + w * 1024]);                    \
    }                                                                         \
  } while (0)

#define COMPUTE(BUF, KT)                                                      \
  do {                                                                        \
    const char* pk = &LDS[BUF][0];                                            \
    const char* pa = &LDS[BUF][PK_BYTES];                                     \
    const int r_loc = w * 16 + l15;                                           \
    _Pragma("unroll")                                                         \
    for (int ks = 0; ks < 2; ++ks) {                                          \
      bf16x8 af[4];                                                           \
      _Pragma("unroll")                                                       \
      for (int m = 0; m < 4; ++m) {                                           \
        int row = m * 16 + l15;                                               \
        int cch = ks * 4 + h;                                                 \
        af[m] = *(const bf16x8*)(pa + row * 128 + ((cch ^ (row & 7)) * 16));  \
      }                                                                       \
      int g = ks * 2 + (h >> 1);                                              \
      const uint* p = (const uint*)(pk + r_loc * 96 + g * 24 + (h & 1) * 12); \
      bf16x8 bfr = dqfrag(p[0], p[1], p[2], NRM[r_loc * NGROW + (KT) * 4 + g]); \
      _Pragma("unroll")                                                       \
      for (int m = 0; m < 4; ++m)                                             \
        acc[m] = __builtin_amdgcn_mfma_f32_16x16x32_bf16(af[m], bfr, acc[m],  \
                                                         0, 0, 0);            \
    }                                                                         \
  } while (0)

  STAGE(0, 0);

  #pragma unroll
  for (int kt = 0; kt < NTILE; ++kt) {
    __syncthreads();                       // drains DMA + lgkm, syncs block
    if (kt + 1 < NTILE) STAGE((kt + 1) & 1, kt + 1);   // in flight across compute
    COMPUTE(kt & 1, kt);
  }

#undef STAGE
#undef STAGE_PK_CHUNK
#undef COMPUTE

  // C/D layout: col = lane&15, row = (lane>>4)*4 + r (verified m89)
  float* pout = partial + (size_t)s * BATCH * OUT_F;
  const int col = nb64 + w * 16 + l15;
  #pragma unroll
  for (int m = 0; m < 4; ++m) {
    int rowb = m * 16 + h * 4;
    #pragma unroll
    for (int r = 0; r < 4; ++r)
      pout[(size_t)(rowb + r) * OUT_F + col] = acc[m][r];
  }
}

template <int KS>
__global__ void __launch_bounds__(256) reduce_kernel(const float* __restrict__ partial,
                                                     const float* __restrict__ bias,
                                                     float* __restrict__ out) {
  int i = blockIdx.x * 256 + threadIdx.x;
  float4 a = ((const float4*)partial)[i];
  #pragma unroll
  for (int s2 = 1; s2 < KS; ++s2) {
    float4 b = ((const float4*)partial)[i + s2 * (BATCH * OUT_F / 4)];
    a.x += b.x; a.y += b.y; a.z += b.z; a.w += b.w;
  }
  float4 bv = ((const float4*)bias)[i & (OUT_F / 4 - 1)];
  a.x += bv.x; a.y += bv.y; a.z += bv.z; a.w += bv.w;
  ((float4*)out)[i] = a;
}

extern "C" void kernel_launch(void* const* d_in, const int* in_sizes, int n_in,
                              void* d_out, int out_size, void* d_ws, size_t ws_size,
                              hipStream_t stream) {
  const float* x     = (const float*)d_in[0];
  const int*   wq    = (const int*)d_in[1];
  const float* wnorm = (const float*)d_in[2];
  const float* bias  = (const float*)d_in[3];
  float* out = (float*)d_out;

  const size_t xb_bytes = (size_t)BATCH * IN_F * 2;  // 1 MB
  ushort* xb      = (ushort*)d_ws;
  float*  partial = (float*)((char*)d_ws + xb_bytes);

  hipLaunchKernelGGL(xcvt_kernel, dim3(BATCH * IN_F / 4 / 256), dim3(256), 0, stream, x, xb);

  const size_t slice_bytes = (size_t)BATCH * OUT_F * 4;  // 2 MB per k-slice
  if (ws_size >= xb_bytes + 16 * slice_bytes) {
    hipLaunchKernelGGL((gemm3b_kernel<16>), dim3(OUT_F / 64, 16), dim3(256), 0, stream,
                       xb, wq, wnorm, partial);
    hipLaunchKernelGGL((reduce_kernel<16>), dim3(BATCH * OUT_F / 4 / 256), dim3(256), 0, stream,
                       partial, bias, out);
  } else if (ws_size >= xb_bytes + 8 * slice_bytes) {
    hipLaunchKernelGGL((gemm3b_kernel<8>), dim3(OUT_F / 64, 8), dim3(256), 0, stream,
                       xb, wq, wnorm, partial);
    hipLaunchKernelGGL((reduce_kernel<8>), dim3(BATCH * OUT_F / 4 / 256), dim3(256), 0, stream,
                       partial, bias, out);
  } else {
    hipLaunchKernelGGL((gemm3b_kernel<4>), dim3(OUT_F / 64, 4), dim3(256), 0, stream,
                       xb, wq, wnorm, partial);
    hipLaunchKernelGGL((reduce_kernel<4>), dim3(BATCH * OUT_F / 4 / 256), dim3(256), 0, stream,
                       partial, bias, out);
  }
}